// Round 2
// baseline (552.049 us; speedup 1.0000x reference)
//
#include <hip/hip_runtime.h>
#include <hip/hip_bf16.h>
#include <stdint.h>

#define SEQ     2048
#define DIN     5
#define HID     64
#define DTC     0.1f
#define BTILE   16
#define NWAVE   4
#define KSTR    72   // LDS row stride in shorts: 64 data + 8 pad; 144 B = 16B-aligned

typedef __attribute__((ext_vector_type(8))) __bf16  bf16x8;
typedef __attribute__((ext_vector_type(8))) short   short8;
typedef __attribute__((ext_vector_type(4))) float   f32x4;
typedef __attribute__((ext_vector_type(4))) int     i32x4;

__device__ __forceinline__ unsigned short f2bf(float f) {
    unsigned int u = __builtin_bit_cast(unsigned int, f);
    unsigned int r = (u + 0x7FFFu + ((u >> 16) & 1u)) >> 16;  // RNE
    return (unsigned short)r;
}

__device__ __forceinline__ float fast_tanh(float x) {
    // tanh(x) = 1 - 2/(e^{2x}+1); exp over/underflow saturates correctly to +-1
    float e = __expf(2.0f * x);
    return 1.0f - 2.0f * __builtin_amdgcn_rcpf(e + 1.0f);
}

__device__ __forceinline__ unsigned int cvt_pk_bf16(float lo, float hi) {
    unsigned int r;
    asm("v_cvt_pk_bf16_f32 %0, %1, %2" : "=v"(r) : "v"(lo), "v"(hi));
    return r;
}

// Workgroup: 4 waves, 16 batch columns. Wave w owns hidden rows [16w,16w+16).
// Per step: h_new = a (.) h + mfma(dtWih|dtb, [x;1]) + mfma(dtWhh, tanh_lds).
// tanh(h) exchanged via double-buffered LDS [b][k] bf16, stride 72 shorts
// (16B-aligned rows), one barrier per step.
__global__ __launch_bounds__(256) void ltc_kernel(
    const float* __restrict__ x,
    const float* __restrict__ tau,
    const float* __restrict__ Wih,
    const float* __restrict__ bih,
    const float* __restrict__ Whh,
    const float* __restrict__ bhh,
    const float* __restrict__ outw,
    const float* __restrict__ outb,
    float* __restrict__ out)
{
    const int tid  = threadIdx.x;
    const int wave = tid >> 6;
    const int lane = tid & 63;
    const int lg   = lane >> 4;   // lane group 0..3
    const int ln   = lane & 15;   // 0..15 (batch col / A-row)
    const int b0   = blockIdx.x * BTILE;

    __shared__ __align__(16) unsigned short tbuf[2][BTILE][KSTR];  // [buf][b][k] bf16
    __shared__ float redbuf[NWAVE][4][BTILE];

    const int jbase = 16 * wave + 4 * lg;   // first C/D row (hidden idx) this lane holds
    const int arow  = 16 * wave + ln;       // A-fragment row (hidden idx)

    float a[4], ow[4];
#pragma unroll
    for (int r = 0; r < 4; ++r) {
        a[r]  = 1.0f - DTC / fabsf(tau[jbase + r]);
        ow[r] = outw[jbase + r];
    }

    // A fragments: lane l holds A[l&15][(l>>4)*8 + q], q=0..7 (m89/m92-verified)
    short8 s0 = {0,0,0,0,0,0,0,0}, s1 = {0,0,0,0,0,0,0,0}, s2 = {0,0,0,0,0,0,0,0};
#pragma unroll
    for (int q = 0; q < 8; ++q) {
        s0[q] = (short)f2bf(DTC * Whh[arow * HID + lg * 8 + q]);
        s1[q] = (short)f2bf(DTC * Whh[arow * HID + 32 + lg * 8 + q]);
    }
    if (lg == 0) {
#pragma unroll
        for (int d = 0; d < DIN; ++d) s2[d] = (short)f2bf(DTC * Wih[arow * DIN + d]);
        s2[5] = (short)f2bf(DTC * (bih[arow] + bhh[arow]));
    }
    const bf16x8 Ahh0 = __builtin_bit_cast(bf16x8, s0);
    const bf16x8 Ahh1 = __builtin_bit_cast(bf16x8, s1);
    const bf16x8 Aix  = __builtin_bit_cast(bf16x8, s2);

    // zero the buffer that step t=0 reads (tanh(h0)=0)
    for (int i = tid; i < BTILE * KSTR; i += 256) (&tbuf[1][0][0])[i] = 0;

    const float* xp = x + (size_t)(b0 + ln) * (SEQ * DIN);
    float px0 = 0.f, px1 = 0.f, px2 = 0.f, px3 = 0.f, px4 = 0.f;
    if (lg == 0) { px0 = xp[0]; px1 = xp[1]; px2 = xp[2]; px3 = xp[3]; px4 = xp[4]; }

    f32x4 h = {0.f, 0.f, 0.f, 0.f};

    for (int t = 0; t < SEQ; ++t) {
        __syncthreads();  // writes of step t-1 visible; reads of step t-1 already done

        // B fragments of tanh(h_{t-1}): lane holds B[(l>>4)*8+q][l&15]
        const unsigned short* tb = &tbuf[(t + 1) & 1][0][0];
        i32x4 r0 = *(const i32x4*)(tb + ln * KSTR + lg * 8);
        i32x4 r1 = *(const i32x4*)(tb + ln * KSTR + 32 + lg * 8);

        // B2 = [x_t; 1; 0...] (only lanes lg==0 hold nonzero k), prefetch x_{t+1}
        short8 bxs = {0,0,0,0,0,0,0,0};
        if (lg == 0) {
            bxs[0] = (short)f2bf(px0); bxs[1] = (short)f2bf(px1);
            bxs[2] = (short)f2bf(px2); bxs[3] = (short)f2bf(px3);
            bxs[4] = (short)f2bf(px4); bxs[5] = (short)0x3F80;  // bf16(1.0)
            if (t + 1 < SEQ) {
                const float* xn = xp + (size_t)(t + 1) * DIN;
                px0 = xn[0]; px1 = xn[1]; px2 = xn[2]; px3 = xn[3]; px4 = xn[4];
            }
        }

        f32x4 c;
#pragma unroll
        for (int r = 0; r < 4; ++r) c[r] = a[r] * h[r];

        c = __builtin_amdgcn_mfma_f32_16x16x32_bf16(Aix,  __builtin_bit_cast(bf16x8, bxs), c, 0, 0, 0);
        c = __builtin_amdgcn_mfma_f32_16x16x32_bf16(Ahh0, __builtin_bit_cast(bf16x8, r0),  c, 0, 0, 0);
        c = __builtin_amdgcn_mfma_f32_16x16x32_bf16(Ahh1, __builtin_bit_cast(bf16x8, r1),  c, 0, 0, 0);
        h = c;

        float t0 = fast_tanh(h[0]);
        float t1 = fast_tanh(h[1]);
        float t2 = fast_tanh(h[2]);
        float t3 = fast_tanh(h[3]);
        unsigned long long w01 =
            ((unsigned long long)cvt_pk_bf16(t2, t3) << 32) | (unsigned long long)cvt_pk_bf16(t0, t1);
        // write own 4 rows (k=jbase..jbase+3) of column ln into current buffer
        *(unsigned long long*)(&tbuf[t & 1][0][0] + ln * KSTR + jbase) = w01;
    }

    // epilogue: out[b] = tanh(h_final) . out_w + out_b
    float part = fast_tanh(h[0]) * ow[0] + fast_tanh(h[1]) * ow[1]
               + fast_tanh(h[2]) * ow[2] + fast_tanh(h[3]) * ow[3];
    redbuf[wave][lg][ln] = part;
    __syncthreads();
    if (tid < BTILE) {
        float s = outb[0];
#pragma unroll
        for (int w = 0; w < NWAVE; ++w)
#pragma unroll
            for (int g = 0; g < 4; ++g) s += redbuf[w][g][tid];
        out[b0 + tid] = s;
    }
}

extern "C" void kernel_launch(void* const* d_in, const int* in_sizes, int n_in,
                              void* d_out, int out_size, void* d_ws, size_t ws_size,
                              hipStream_t stream) {
    const float* x    = (const float*)d_in[0];
    const float* tau  = (const float*)d_in[1];
    const float* Wih  = (const float*)d_in[2];
    const float* bih  = (const float*)d_in[3];
    const float* Whh  = (const float*)d_in[4];
    const float* bhh  = (const float*)d_in[5];
    const float* outw = (const float*)d_in[6];
    const float* outb = (const float*)d_in[7];
    float* out = (float*)d_out;

    const int batch = in_sizes[0] / (SEQ * DIN);   // 4096
    ltc_kernel<<<batch / BTILE, NWAVE * 64, 0, stream>>>(x, tau, Wih, bih, Whh, bhh, outw, outb, out);
}

// Round 3
// 523.868 us; speedup vs baseline: 1.0538x; 1.0538x over previous
//
#include <hip/hip_runtime.h>
#include <hip/hip_bf16.h>
#include <stdint.h>

#define SEQ     2048
#define DIN     5
#define HID     64
#define DTC     0.1f
#define BTILE   16
#define NWAVE   4

typedef __attribute__((ext_vector_type(8))) __bf16  bf16x8;
typedef __attribute__((ext_vector_type(8))) short   short8;
typedef __attribute__((ext_vector_type(4))) float   f32x4;
typedef __attribute__((ext_vector_type(4))) int     i32x4;
typedef unsigned long long u64;

__device__ __forceinline__ unsigned short f2bf(float f) {
    unsigned int u = __builtin_bit_cast(unsigned int, f);
    return (unsigned short)((u + 0x7FFFu + ((u >> 16) & 1u)) >> 16);  // RNE
}

__device__ __forceinline__ float fast_tanh(float x) {
    // tanh(x) = 1 - 2/(e^{2x}+1); saturates correctly at +-1
    float e = __expf(2.0f * x);
    return 1.0f - 2.0f * __builtin_amdgcn_rcpf(e + 1.0f);
}

__device__ __forceinline__ unsigned int cvt_pk_bf16(float lo, float hi) {
    unsigned int r;
    asm("v_cvt_pk_bf16_f32 %0, %1, %2" : "=v"(r) : "v"(lo), "v"(hi));
    return r;
}

// 4 waves / 16 batch cols per block; wave w owns hidden rows [16w,16w+16).
// tanh exchange via double-buffered LDS stored in B-FRAGMENT-LINEAR order:
// reading lane l reads 16B at byte 16*l (k-tile0) and 1024+16*l (k-tile1) —
// conflict-free by construction. One barrier per step.
__global__ __launch_bounds__(256) void ltc_kernel(
    const float* __restrict__ x,
    const float* __restrict__ tau,
    const float* __restrict__ Wih,
    const float* __restrict__ bih,
    const float* __restrict__ Whh,
    const float* __restrict__ bhh,
    const float* __restrict__ outw,
    const float* __restrict__ outb,
    float* __restrict__ out)
{
    const int tid  = threadIdx.x;
    const int wave = tid >> 6;
    const int lane = tid & 63;
    const int lg   = lane >> 4;
    const int ln   = lane & 15;
    const int b0   = blockIdx.x * BTILE;

    __shared__ __align__(16) unsigned short sbuf[2][1024];  // 2 x 2KB fragment buffers
    __shared__ float redbuf[NWAVE][4][BTILE];

    const int jbase = 16 * wave + 4 * lg;   // first C/D row (hidden idx) of this lane
    const int arow  = 16 * wave + ln;       // A-fragment row (hidden idx)

    float a[4], ow[4];
#pragma unroll
    for (int r = 0; r < 4; ++r) {
        a[r]  = 1.0f - DTC / fabsf(tau[jbase + r]);
        ow[r] = outw[jbase + r];
    }

    // A fragments: lane l holds A[l&15][(l>>4)*8 + q]  (m89/m92-verified, passed r2)
    short8 s0 = {0,0,0,0,0,0,0,0}, s1 = {0,0,0,0,0,0,0,0}, s2 = {0,0,0,0,0,0,0,0};
#pragma unroll
    for (int q = 0; q < 8; ++q) {
        s0[q] = (short)f2bf(DTC * Whh[arow * HID + lg * 8 + q]);
        s1[q] = (short)f2bf(DTC * Whh[arow * HID + 32 + lg * 8 + q]);
    }
    if (lg == 0) {
#pragma unroll
        for (int d = 0; d < DIN; ++d) s2[d] = (short)f2bf(DTC * Wih[arow * DIN + d]);
        s2[5] = (short)f2bf(DTC * (bih[arow] + bhh[arow]));
    }
    const bf16x8 Ahh0 = __builtin_bit_cast(bf16x8, s0);
    const bf16x8 Ahh1 = __builtin_bit_cast(bf16x8, s1);
    const bf16x8 Aix  = __builtin_bit_cast(bf16x8, s2);

    // write address (byte offset inside one parity buffer):
    // value for k=jbase..jbase+3, col=ln goes to reader lane (16*((k&31)>>3) + ln),
    // chunk half (jbase>>2)&1, region (jbase>=32)*1024.
    const int wbyte = ((jbase >= 32) ? 1024 : 0) + (((jbase & 31) >> 3) * 256)
                    + ln * 16 + (((jbase >> 2) & 1) * 8);
    char* const wp0 = (char*)sbuf[0] + wbyte;
    char* const wp1 = (char*)sbuf[1] + wbyte;
    const char* const rp0 = (const char*)sbuf[0] + lane * 16;
    const char* const rp1 = (const char*)sbuf[1] + lane * 16;

    // zero parity-1 buffer (read at t=0: tanh(h0)=0)
    ((u64*)sbuf[1])[tid] = 0ULL;

    const unsigned int lmask = (lg == 0) ? 0xFFFFFFFFu : 0u;

    // depth-2 x prefetch, all lanes unconditional (lg!=0 lanes read same addrs -> broadcast)
    const float* xb = x + (size_t)(b0 + ln) * (SEQ * DIN);
    float eA0 = xb[0], eA1 = xb[1], eA2 = xb[2], eA3 = xb[3], eA4 = xb[4];
    float oA0 = xb[5], oA1 = xb[6], oA2 = xb[7], oA3 = xb[8], oA4 = xb[9];
    const float* xnext = xb + 2 * DIN;   // -> x[t=2]

    f32x4 h = {0.f, 0.f, 0.f, 0.f};

#define STEP(PAR, P0, P1, P2, P3, P4, PF, XOFF)                                    \
    {                                                                              \
        __syncthreads();                                                           \
        const char* rb = (PAR) ? rp0 : rp1;        /* read parity = !PAR */        \
        i32x4 r0 = *(const i32x4*)(rb);                                            \
        i32x4 r1 = *(const i32x4*)(rb + 1024);                                     \
        unsigned int bu0 = cvt_pk_bf16(P0, P1) & lmask;                            \
        unsigned int bu1 = cvt_pk_bf16(P2, P3) & lmask;                            \
        unsigned int bu2 = cvt_pk_bf16(P4, 1.0f) & lmask;                          \
        i32x4 bx = { (int)bu0, (int)bu1, (int)bu2, 0 };                            \
        if (PF) { P0 = xnext[(XOFF)+0]; P1 = xnext[(XOFF)+1]; P2 = xnext[(XOFF)+2];\
                  P3 = xnext[(XOFF)+3]; P4 = xnext[(XOFF)+4]; }                    \
        f32x4 c;                                                                   \
        c[0] = a[0]*h[0]; c[1] = a[1]*h[1]; c[2] = a[2]*h[2]; c[3] = a[3]*h[3];    \
        c = __builtin_amdgcn_mfma_f32_16x16x32_bf16(Aix,  __builtin_bit_cast(bf16x8, bx), c, 0, 0, 0); \
        c = __builtin_amdgcn_mfma_f32_16x16x32_bf16(Ahh0, __builtin_bit_cast(bf16x8, r0), c, 0, 0, 0); \
        c = __builtin_amdgcn_mfma_f32_16x16x32_bf16(Ahh1, __builtin_bit_cast(bf16x8, r1), c, 0, 0, 0); \
        h = c;                                                                     \
        float t0 = fast_tanh(h[0]), t1 = fast_tanh(h[1]);                          \
        float t2 = fast_tanh(h[2]), t3 = fast_tanh(h[3]);                          \
        u64 w01 = ((u64)cvt_pk_bf16(t2, t3) << 32) | (u64)cvt_pk_bf16(t0, t1);     \
        *(u64*)((PAR) ? wp1 : wp0) = w01;                                          \
    }

    for (int t = 0; t < SEQ - 2; t += 2) {
        STEP(0, eA0, eA1, eA2, eA3, eA4, true, 0)
        STEP(1, oA0, oA1, oA2, oA3, oA4, true, DIN)
        xnext += 2 * DIN;
    }
    STEP(0, eA0, eA1, eA2, eA3, eA4, false, 0)   // t = SEQ-2
    STEP(1, oA0, oA1, oA2, oA3, oA4, false, 0)   // t = SEQ-1
#undef STEP

    // epilogue: out[b] = tanh(h_final) . out_w + out_b
    float part = fast_tanh(h[0]) * ow[0] + fast_tanh(h[1]) * ow[1]
               + fast_tanh(h[2]) * ow[2] + fast_tanh(h[3]) * ow[3];
    redbuf[wave][lg][ln] = part;
    __syncthreads();
    if (tid < BTILE) {
        float s = outb[0];
#pragma unroll
        for (int w = 0; w < NWAVE; ++w)
#pragma unroll
            for (int g = 0; g < 4; ++g) s += redbuf[w][g][tid];
        out[b0 + tid] = s;
    }
}

extern "C" void kernel_launch(void* const* d_in, const int* in_sizes, int n_in,
                              void* d_out, int out_size, void* d_ws, size_t ws_size,
                              hipStream_t stream) {
    const float* x    = (const float*)d_in[0];
    const float* tau  = (const float*)d_in[1];
    const float* Wih  = (const float*)d_in[2];
    const float* bih  = (const float*)d_in[3];
    const float* Whh  = (const float*)d_in[4];
    const float* bhh  = (const float*)d_in[5];
    const float* outw = (const float*)d_in[6];
    const float* outb = (const float*)d_in[7];
    float* out = (float*)d_out;

    const int batch = in_sizes[0] / (SEQ * DIN);   // 4096
    ltc_kernel<<<batch / BTILE, NWAVE * 64, 0, stream>>>(x, tau, Wih, bih, Whh, bhh, outw, outb, out);
}